// Round 1
// baseline (2398.662 us; speedup 1.0000x reference)
//
#include <hip/hip_runtime.h>
#include <math.h>

#define DD 768
#define NT 256

// ---------------------------------------------------------------------------
// Stage 1: score matrix S[i,j] for all (left i, right j) pairs.
// S[i,j] = sum_d f(n_d, g_d, cmp_d) * Wl_d  (b_lin omitted: argmax-invariant)
//   cmp = |L[i,:]-R[j,:]|, n = cmp@Wn + bn, g_pre = cmp@Wg + bg
//   f = relu(n)*sigmoid(g_pre) + (1-sigmoid(g_pre))*cmp
// Block: one i, 64-j tile, 128-d tile. Grid (4, 6, 256). S accumulated atomically.
// ---------------------------------------------------------------------------
__global__ __launch_bounds__(256) void score_kernel(
    const float* __restrict__ L, const float* __restrict__ R,
    const float* __restrict__ Wn, const float* __restrict__ bn,
    const float* __restrict__ Wg, const float* __restrict__ bg,
    const float* __restrict__ Wl, float* __restrict__ S)
{
  const int jt = blockIdx.x;   // 4 tiles of 64 j
  const int dt = blockIdx.y;   // 6 tiles of 128 d
  const int i  = blockIdx.z;   // 256 left rows
  const int tid = threadIdx.x;
  const int tx = tid & 15;     // d micro (8 cols: tx*4+dd / 64+tx*4+dd)
  const int ty = tid >> 4;     // j micro (4 rows: ty*4+jj)
  const int j0 = jt * 64;
  const int d0 = dt * 128;

  __shared__ float As[16][68];    // [k][j], +4 pad keeps float4 alignment
  __shared__ float Bns[16][128];  // [k][d]
  __shared__ float Bgs[16][128];

  float accn[4][8] = {};
  float accg[4][8] = {};

  const int lk  = tid & 15;
  const int lj  = tid >> 4;    // 0..15
  const int ld  = tid & 127;
  const int lkq = tid >> 7;    // 0..1

  for (int k0 = 0; k0 < DD; k0 += 16) {
    // A' tile: |L[i,k]-R[j,k]|, 64j x 16k
    float Lv = L[i*DD + k0 + lk];
    #pragma unroll
    for (int p = 0; p < 4; ++p) {
      int j = lj + 16*p;
      As[lk][j] = fabsf(Lv - R[(size_t)(j0+j)*DD + k0 + lk]);
    }
    // weight tiles: 16k x 128d, coalesced 512B rows
    #pragma unroll
    for (int p = 0; p < 8; ++p) {
      int k = lkq*8 + p;
      Bns[k][ld] = Wn[(size_t)(k0+k)*DD + d0 + ld];
      Bgs[k][ld] = Wg[(size_t)(k0+k)*DD + d0 + ld];
    }
    __syncthreads();
    #pragma unroll
    for (int k = 0; k < 16; ++k) {
      float4 a4 = *(const float4*)&As[k][ty*4];
      float4 n0 = *(const float4*)&Bns[k][tx*4];
      float4 n1 = *(const float4*)&Bns[k][64 + tx*4];
      float4 g0 = *(const float4*)&Bgs[k][tx*4];
      float4 g1 = *(const float4*)&Bgs[k][64 + tx*4];
      float av[4] = {a4.x,a4.y,a4.z,a4.w};
      float nv[8] = {n0.x,n0.y,n0.z,n0.w,n1.x,n1.y,n1.z,n1.w};
      float gv[8] = {g0.x,g0.y,g0.z,g0.w,g1.x,g1.y,g1.z,g1.w};
      #pragma unroll
      for (int jj = 0; jj < 4; ++jj)
        #pragma unroll
        for (int dd = 0; dd < 8; ++dd) {
          accn[jj][dd] = fmaf(av[jj], nv[dd], accn[jj][dd]);
          accg[jj][dd] = fmaf(av[jj], gv[dd], accg[jj][dd]);
        }
    }
    __syncthreads();
  }

  // epilogue: highway + W_lin contraction over this block's 128 d, reduce, atomic
  #pragma unroll
  for (int jj = 0; jj < 4; ++jj) {
    int j = j0 + ty*4 + jj;
    float sc = 0.f;
    #pragma unroll
    for (int dd = 0; dd < 8; ++dd) {
      int dl = (dd < 4) ? (tx*4 + dd) : (64 + tx*4 + (dd - 4));
      int d = d0 + dl;
      float n  = accn[jj][dd] + bn[d];
      float gp = accg[jj][dd] + bg[d];
      float h  = fmaxf(n, 0.f);
      float g  = 1.f / (1.f + expf(-gp));
      float c  = fabsf(L[i*DD + d] - R[(size_t)j*DD + d]);
      sc += (h*g + (1.f - g)*c) * Wl[d];
    }
    #pragma unroll
    for (int m = 1; m < 16; m <<= 1) sc += __shfl_xor(sc, m, 16);
    if (tx == 0) atomicAdd(&S[i*NT + j], sc);
  }
}

// ---------------------------------------------------------------------------
// Stage 2: argmax over rows (left: argmax_j S[i,j]) and cols (right: argmax_i).
// First-max-index tie-break to match jnp.argmax.
// ---------------------------------------------------------------------------
__global__ __launch_bounds__(256) void argmax_kernel(const float* __restrict__ S,
    int* __restrict__ idxL, int* __restrict__ idxR)
{
  int b = blockIdx.x;   // 0..255: row i;  256..511: col j
  int t = threadIdx.x;
  float v = (b < NT) ? S[b*NT + t] : S[t*NT + (b - NT)];
  int idx = t;
  #pragma unroll
  for (int m = 1; m < 64; m <<= 1) {
    float ov = __shfl_xor(v, m, 64);
    int   oi = __shfl_xor(idx, m, 64);
    if (ov > v || (ov == v && oi < idx)) { v = ov; idx = oi; }
  }
  __shared__ float sv[4]; __shared__ int si[4];
  if ((t & 63) == 0) { sv[t>>6] = v; si[t>>6] = idx; }
  __syncthreads();
  if (t == 0) {
    #pragma unroll
    for (int w = 1; w < 4; ++w)
      if (sv[w] > v || (sv[w] == v && si[w] < idx)) { v = sv[w]; idx = si[w]; }
    if (b < NT) idxL[b] = idx; else idxR[b - NT] = idx;
  }
}

// ---------------------------------------------------------------------------
// Stage 3: ragged per-attribute softmax-weighted reduction of cmp rows.
// One block per side. cmp rows recomputed from embeddings via matched index.
// x[0:3072] = left reps, x[3072:6144] = right reps.
// ---------------------------------------------------------------------------
__global__ __launch_bounds__(256) void attr_kernel(
    const float* __restrict__ Lemb, const float* __restrict__ Remb,
    const float* __restrict__ AEl, const float* __restrict__ AEr,
    const int* __restrict__ lensL, const int* __restrict__ lensR,
    const int* __restrict__ idxL, const int* __restrict__ idxR,
    const float* __restrict__ empty, float* __restrict__ x)
{
  const int side = blockIdx.x;
  const float* tok = side ? Remb : Lemb;
  const float* oth = side ? Lemb : Remb;
  const float* AE  = side ? AEr  : AEl;
  const int* lens  = side ? lensR : lensL;
  const int* midx  = side ? idxR  : idxL;
  float* xo = x + side * 4 * DD;
  const int t = threadIdx.x;

  __shared__ int   segS[NT];
  __shared__ int   idxS[NT];
  __shared__ float scS[NT];
  __shared__ float wS[NT];
  __shared__ float mS[4], zS[4];

  int l0 = lens[0], l1 = lens[1], l2 = lens[2];
  int c0 = l0, c1 = l0 + l1, c2 = c1 + l2;
  int seg = (t < c0) ? 0 : (t < c1) ? 1 : (t < c2) ? 2 : 3;
  segS[t] = seg;
  idxS[t] = midx[t];
  float s = 0.f;
  for (int k = 0; k < DD; ++k) s += tok[t*DD + k] * AE[seg*DD + k];
  scS[t] = s;
  __syncthreads();
  if (t < 4) {
    float m = -INFINITY;
    for (int u = 0; u < NT; ++u) if (segS[u] == t) m = fmaxf(m, scS[u]);
    mS[t] = m;
    float z = 0.f;
    for (int u = 0; u < NT; ++u) if (segS[u] == t) z += expf(scS[u] - m);
    zS[t] = z;
  }
  __syncthreads();
  wS[t] = expf(scS[t] - mS[seg]) / zS[seg];
  __syncthreads();
  // weighted reps: threads cover d (3 passes of 256)
  for (int p = 0; p < 3; ++p) {
    int d = p*NT + t;
    float a0 = 0.f, a1 = 0.f, a2 = 0.f, a3 = 0.f;
    for (int u = 0; u < NT; ++u) {
      float c = fabsf(tok[u*DD + d] - oth[(size_t)idxS[u]*DD + d]);
      float wc = wS[u] * c;
      int a = segS[u];
      if      (a == 0) a0 += wc;
      else if (a == 1) a1 += wc;
      else if (a == 2) a2 += wc;
      else             a3 += wc;
    }
    xo[0*DD + d] = (lens[0] > 0) ? a0 : empty[d];
    xo[1*DD + d] = (lens[1] > 0) ? a1 : empty[d];
    xo[2*DD + d] = (lens[2] > 0) ? a2 : empty[d];
    xo[3*DD + d] = (lens[3] > 0) ? a3 : empty[d];
  }
}

// ---------------------------------------------------------------------------
// Stage 4a: entity matvecs yn = x@Wn_ent, yg = x@Wg_ent (6144x6144 each).
// K-split across blocks with atomic accumulation. HBM-bound (302 MB weights).
// ---------------------------------------------------------------------------
#define DE 6144
__global__ __launch_bounds__(256) void ent_matvec(
    const float* __restrict__ x,
    const float* __restrict__ Wn, const float* __restrict__ Wg,
    float* __restrict__ yn, float* __restrict__ yg)
{
  __shared__ float xs[192];
  const int db = blockIdx.x;   // 24 blocks of 256 cols
  const int kb = blockIdx.y;   // 32 chunks of 192 k
  const int tid = threadIdx.x;
  if (tid < 192) xs[tid] = x[kb*192 + tid];
  __syncthreads();
  const int d = db*256 + tid;
  float an = 0.f, ag = 0.f;
  size_t base = (size_t)kb * 192 * DE + d;
  for (int kk = 0; kk < 192; ++kk) {
    float xv = xs[kk];
    an = fmaf(xv, Wn[base + (size_t)kk*DE], an);
    ag = fmaf(xv, Wg[base + (size_t)kk*DE], ag);
  }
  atomicAdd(&yn[d], an);
  atomicAdd(&yg[d], ag);
}

// ---------------------------------------------------------------------------
// Stage 4b: entity highway + logits + softmax -> out[2].
// ---------------------------------------------------------------------------
__global__ __launch_bounds__(256) void final_kernel(
    const float* __restrict__ x, const float* __restrict__ yn,
    const float* __restrict__ yg, const float* __restrict__ bn,
    const float* __restrict__ bg, const float* __restrict__ Wl,
    const float* __restrict__ bl, float* __restrict__ out)
{
  const int tid = threadIdx.x;
  float a0 = 0.f, a1 = 0.f;
  for (int p = 0; p < DE/256; ++p) {
    int d = p*256 + tid;
    float n  = yn[d] + bn[d];
    float gp = yg[d] + bg[d];
    float h  = fmaxf(n, 0.f);
    float g  = 1.f / (1.f + expf(-gp));
    float hw = h*g + (1.f - g)*x[d];
    a0 += hw * Wl[d*2 + 0];
    a1 += hw * Wl[d*2 + 1];
  }
  #pragma unroll
  for (int m = 1; m < 64; m <<= 1) {
    a0 += __shfl_xor(a0, m, 64);
    a1 += __shfl_xor(a1, m, 64);
  }
  __shared__ float s0[4], s1[4];
  if ((tid & 63) == 0) { s0[tid>>6] = a0; s1[tid>>6] = a1; }
  __syncthreads();
  if (tid == 0) {
    for (int w = 1; w < 4; ++w) { a0 += s0[w]; a1 += s1[w]; }
    float l0 = a0 + bl[0], l1 = a1 + bl[1];
    float m = fmaxf(l0, l1);
    float e0 = expf(l0 - m), e1 = expf(l1 - m);
    out[0] = e0 / (e0 + e1);
    out[1] = e1 / (e0 + e1);
  }
}

// ---------------------------------------------------------------------------
extern "C" void kernel_launch(void* const* d_in, const int* in_sizes, int n_in,
                              void* d_out, int out_size, void* d_ws, size_t ws_size,
                              hipStream_t stream) {
  const float* Lemb   = (const float*)d_in[0];
  const float* Remb   = (const float*)d_in[1];
  const float* Wn_tok = (const float*)d_in[2];
  const float* bn_tok = (const float*)d_in[3];
  const float* Wg_tok = (const float*)d_in[4];
  const float* bg_tok = (const float*)d_in[5];
  const float* Wl_tok = (const float*)d_in[6];
  // d_in[7] = b_lin_tok: constant shift, argmax-invariant -> unused
  const float* AEl    = (const float*)d_in[8];
  const float* AEr    = (const float*)d_in[9];
  const float* Wn_ent = (const float*)d_in[10];
  const float* bn_ent = (const float*)d_in[11];
  const float* Wg_ent = (const float*)d_in[12];
  const float* bg_ent = (const float*)d_in[13];
  const float* Wl_ent = (const float*)d_in[14];
  const float* bl_ent = (const float*)d_in[15];
  const float* empty  = (const float*)d_in[16];
  const int*   lensL  = (const int*)d_in[17];
  const int*   lensR  = (const int*)d_in[18];

  float* ws   = (float*)d_ws;
  float* S    = ws;                       // 65536 floats
  int*   idxL = (int*)(ws + 65536);       // 256
  int*   idxR = (int*)(ws + 65792);       // 256
  float* x    = ws + 66048;               // 6144
  float* yn   = ws + 72192;               // 6144
  float* yg   = ws + 78336;               // 6144  (contiguous with yn)

  hipMemsetAsync(S, 0, (size_t)65536 * sizeof(float), stream);
  hipMemsetAsync(yn, 0, (size_t)2 * DE * sizeof(float), stream);

  score_kernel<<<dim3(4, 6, 256), 256, 0, stream>>>(
      Lemb, Remb, Wn_tok, bn_tok, Wg_tok, bg_tok, Wl_tok, S);
  argmax_kernel<<<512, 256, 0, stream>>>(S, idxL, idxR);
  attr_kernel<<<2, 256, 0, stream>>>(
      Lemb, Remb, AEl, AEr, lensL, lensR, idxL, idxR, empty, x);
  ent_matvec<<<dim3(24, 32), 256, 0, stream>>>(x, Wn_ent, Wg_ent, yn, yg);
  final_kernel<<<1, 256, 0, stream>>>(
      x, yn, yg, bn_ent, bg_ent, Wl_ent, bl_ent, (float*)d_out);
}

// Round 2
// 672.779 us; speedup vs baseline: 3.5653x; 3.5653x over previous
//
#include <hip/hip_runtime.h>
#include <math.h>

#define DD 768
#define NT 256
#define DE 6144

typedef _Float16 half8 __attribute__((ext_vector_type(8)));
typedef float floatx4 __attribute__((ext_vector_type(4)));

// ---------------------------------------------------------------------------
// Prep: transpose + fp16-convert token weights: WT[d][k] = (f16)W[k][d].
// Makes B-fragments contiguous in LDS (ds_read_b128) in the MFMA kernel.
// ---------------------------------------------------------------------------
__global__ __launch_bounds__(256) void transpose_cvt(
    const float* __restrict__ Wn, const float* __restrict__ Wg,
    _Float16* __restrict__ WnT, _Float16* __restrict__ WgT)
{
  const float* W = blockIdx.z ? Wg : Wn;
  _Float16* WT = blockIdx.z ? WgT : WnT;
  __shared__ float tile[32][33];
  const int tx = threadIdx.x & 31, ty = threadIdx.x >> 5;
  const int d0 = blockIdx.x * 32, k0 = blockIdx.y * 32;
  #pragma unroll
  for (int p = 0; p < 4; ++p)
    tile[ty + p*8][tx] = W[(size_t)(k0 + ty + p*8)*DD + d0 + tx];
  __syncthreads();
  #pragma unroll
  for (int p = 0; p < 4; ++p)
    WT[(size_t)(d0 + ty + p*8)*DD + k0 + tx] = (_Float16)tile[tx][ty + p*8];
}

// ---------------------------------------------------------------------------
// Stage 1: score matrix via f16 MFMA. Block = (i, 128 j, 128 d), K=768.
// n = cmp@Wn, g_pre = cmp@Wg accumulated fp32 in MFMA; epilogue applies
// highway with EXACT fp32 cmp bypass and contracts with Wl into S[i,j].
// ---------------------------------------------------------------------------
__global__ __launch_bounds__(256, 2) void score_mfma(
    const float* __restrict__ L, const float* __restrict__ R,
    const _Float16* __restrict__ WnT, const _Float16* __restrict__ WgT,
    const float* __restrict__ bn, const float* __restrict__ bg,
    const float* __restrict__ Wl, float* __restrict__ S)
{
  const int jbase = blockIdx.x * 128;
  const int dbase = blockIdx.y * 128;
  const int i     = blockIdx.z;
  const int tid   = threadIdx.x;

  __shared__ _Float16 As [128*72];   // [j][k], stride 72 (2-way banks = free)
  __shared__ _Float16 Bns[128*72];   // [d][k]
  __shared__ _Float16 Bgs[128*72];

  floatx4 accn[4][4] = {};
  floatx4 accg[4][4] = {};

  const int kg = tid & 7;     // 8-wide k-group (8 f16 = 16 B)
  const int rl = tid >> 3;    // 0..31 row within tile quarter

  const int lane = tid & 63;
  const int wid  = tid >> 6;
  const int wj = (wid & 1) * 64;   // wave's j-quadrant
  const int wd = (wid >> 1) * 64;  // wave's d-quadrant
  const int m = lane & 15;
  const int q = lane >> 4;

  for (int k0 = 0; k0 < DD; k0 += 64) {
    // ---- stage A: cmp tile 128j x 64k, fp32 sources -> fp16 LDS
    float l0[8];
    *(float4*)&l0[0] = *(const float4*)&L[i*DD + k0 + kg*8];
    *(float4*)&l0[4] = *(const float4*)&L[i*DD + k0 + kg*8 + 4];
    #pragma unroll
    for (int rep = 0; rep < 4; ++rep) {
      const int row = rl + rep*32;
      float rv[8];
      const float* Rrow = &R[(size_t)(jbase + row)*DD + k0 + kg*8];
      *(float4*)&rv[0] = *(const float4*)&Rrow[0];
      *(float4*)&rv[4] = *(const float4*)&Rrow[4];
      half8 h;
      #pragma unroll
      for (int e = 0; e < 8; ++e) h[e] = (_Float16)fabsf(l0[e] - rv[e]);
      *(half8*)&As[row*72 + kg*8] = h;
    }
    // ---- stage B: Wn/Wg transposed chunks 128d x 64k (pre-converted fp16)
    #pragma unroll
    for (int rep = 0; rep < 4; ++rep) {
      const int row = rl + rep*32;
      *(half8*)&Bns[row*72 + kg*8] =
          *(const half8*)&WnT[(size_t)(dbase + row)*DD + k0 + kg*8];
      *(half8*)&Bgs[row*72 + kg*8] =
          *(const half8*)&WgT[(size_t)(dbase + row)*DD + k0 + kg*8];
    }
    __syncthreads();
    // ---- MFMA: wave covers 64j x 64d = 4x4 tiles of 16x16, two matrices
    #pragma unroll
    for (int kk = 0; kk < 64; kk += 32) {
      half8 af[4], bfn[4], bfg[4];
      #pragma unroll
      for (int t4 = 0; t4 < 4; ++t4)
        af[t4] = *(const half8*)&As[(wj + t4*16 + m)*72 + kk + q*8];
      #pragma unroll
      for (int t4 = 0; t4 < 4; ++t4) {
        bfn[t4] = *(const half8*)&Bns[(wd + t4*16 + m)*72 + kk + q*8];
        bfg[t4] = *(const half8*)&Bgs[(wd + t4*16 + m)*72 + kk + q*8];
      }
      #pragma unroll
      for (int tj = 0; tj < 4; ++tj)
        #pragma unroll
        for (int td = 0; td < 4; ++td) {
          accn[tj][td] = __builtin_amdgcn_mfma_f32_16x16x32_f16(
              af[tj], bfn[td], accn[tj][td], 0, 0, 0);
          accg[tj][td] = __builtin_amdgcn_mfma_f32_16x16x32_f16(
              af[tj], bfg[td], accg[tj][td], 0, 0, 0);
        }
    }
    __syncthreads();
  }

  // ---- epilogue: highway + Wl contraction; C layout col=lane&15, row=q*4+r
  float bnv[4], bgv[4], wlv[4], lv[4];
  int dv[4];
  #pragma unroll
  for (int td = 0; td < 4; ++td) {
    const int d = dbase + wd + td*16 + m;
    dv[td] = d; bnv[td] = bn[d]; bgv[td] = bg[d]; wlv[td] = Wl[d];
    lv[td] = L[i*DD + d];
  }
  const int jb = jbase + wj;
  #pragma unroll
  for (int tj = 0; tj < 4; ++tj) {
    #pragma unroll
    for (int r = 0; r < 4; ++r) {
      const int j = jb + tj*16 + q*4 + r;
      float sc = 0.f;
      #pragma unroll
      for (int td = 0; td < 4; ++td) {
        const float nv = accn[tj][td][r] + bnv[td];
        const float gp = accg[tj][td][r] + bgv[td];
        const float g  = 1.f / (1.f + __expf(-gp));
        const float c  = fabsf(lv[td] - R[(size_t)j*DD + dv[td]]);
        sc += (fmaxf(nv, 0.f)*g + (1.f - g)*c) * wlv[td];
      }
      sc += __shfl_xor(sc, 1, 16);
      sc += __shfl_xor(sc, 2, 16);
      sc += __shfl_xor(sc, 4, 16);
      sc += __shfl_xor(sc, 8, 16);
      if (m == 0) atomicAdd(&S[i*NT + j], sc);
    }
  }
}

// ---------------------------------------------------------------------------
// Stage 2: argmax over rows (left) and cols (right), first-index tie-break.
// ---------------------------------------------------------------------------
__global__ __launch_bounds__(256) void argmax_kernel(const float* __restrict__ S,
    int* __restrict__ idxL, int* __restrict__ idxR)
{
  int b = blockIdx.x;
  int t = threadIdx.x;
  float v = (b < NT) ? S[b*NT + t] : S[t*NT + (b - NT)];
  int idx = t;
  #pragma unroll
  for (int mm = 1; mm < 64; mm <<= 1) {
    float ov = __shfl_xor(v, mm, 64);
    int   oi = __shfl_xor(idx, mm, 64);
    if (ov > v || (ov == v && oi < idx)) { v = ov; idx = oi; }
  }
  __shared__ float sv[4]; __shared__ int si[4];
  if ((t & 63) == 0) { sv[t>>6] = v; si[t>>6] = idx; }
  __syncthreads();
  if (t == 0) {
    #pragma unroll
    for (int w = 1; w < 4; ++w)
      if (sv[w] > v || (sv[w] == v && si[w] < idx)) { v = sv[w]; idx = si[w]; }
    if (b < NT) idxL[b] = idx; else idxR[b - NT] = idx;
  }
}

// ---------------------------------------------------------------------------
// Stage 3a: per-token attribute scores + segment softmax weights (2 blocks).
// ---------------------------------------------------------------------------
__global__ __launch_bounds__(256) void attr_score(
    const float* __restrict__ Lemb, const float* __restrict__ Remb,
    const float* __restrict__ AEl, const float* __restrict__ AEr,
    const int* __restrict__ lensL, const int* __restrict__ lensR,
    float* __restrict__ wS, int* __restrict__ segA)
{
  const int side = blockIdx.x;
  const float* tok = side ? Remb : Lemb;
  const float* AE  = side ? AEr  : AEl;
  const int* lens  = side ? lensR : lensL;
  const int t = threadIdx.x;
  const int c0 = lens[0], c1 = c0 + lens[1], c2 = c1 + lens[2];
  const int seg = (t < c0) ? 0 : (t < c1) ? 1 : (t < c2) ? 2 : 3;
  float s = 0.f;
  const float4* tr = (const float4*)&tok[(size_t)t*DD];
  const float4* ar = (const float4*)&AE[(size_t)seg*DD];
  for (int k = 0; k < DD/4; ++k) {
    float4 a = tr[k], b = ar[k];
    s += a.x*b.x + a.y*b.y + a.z*b.z + a.w*b.w;
  }
  __shared__ float scS[NT]; __shared__ int segS[NT];
  __shared__ float mS[4], zS[4];
  scS[t] = s; segS[t] = seg;
  __syncthreads();
  if (t < 4) {
    float m = -INFINITY;
    for (int u = 0; u < NT; ++u) if (segS[u] == t) m = fmaxf(m, scS[u]);
    mS[t] = m;
    float z = 0.f;
    for (int u = 0; u < NT; ++u) if (segS[u] == t) z += __expf(scS[u] - m);
    zS[t] = z;
  }
  __syncthreads();
  wS[side*NT + t] = __expf(s - mS[seg]) / zS[seg];
  segA[side*NT + t] = seg;
}

// ---------------------------------------------------------------------------
// Stage 3b: weighted segment reduction of cmp rows, d-parallel (2x12 blocks).
// ---------------------------------------------------------------------------
__global__ __launch_bounds__(256) void attr_reduce(
    const float* __restrict__ Lemb, const float* __restrict__ Remb,
    const int* __restrict__ lensL, const int* __restrict__ lensR,
    const int* __restrict__ idxL, const int* __restrict__ idxR,
    const float* __restrict__ wS, const int* __restrict__ segA,
    const float* __restrict__ empty, float* __restrict__ x)
{
  const int side = blockIdx.x;
  const float* tok = side ? Remb : Lemb;
  const float* oth = side ? Lemb : Remb;
  const int* lens  = side ? lensR : lensL;
  const int* idx   = side ? idxR  : idxL;
  const float* w   = wS + side*NT;
  const int* sg    = segA + side*NT;
  float* xo = x + side*4*DD;
  const int t = threadIdx.x;
  const int dl = t & 63, uq = t >> 6;
  const int d = blockIdx.y*64 + dl;
  float a0 = 0.f, a1 = 0.f, a2 = 0.f, a3 = 0.f;
  for (int u = uq*64; u < uq*64 + 64; ++u) {
    const float c = fabsf(tok[(size_t)u*DD + d] - oth[(size_t)idx[u]*DD + d]);
    const float wc = w[u] * c;
    const int s = sg[u];
    a0 += (s == 0) ? wc : 0.f;
    a1 += (s == 1) ? wc : 0.f;
    a2 += (s == 2) ? wc : 0.f;
    a3 += (s == 3) ? wc : 0.f;
  }
  __shared__ float red[4][4][64];
  red[uq][0][dl] = a0; red[uq][1][dl] = a1;
  red[uq][2][dl] = a2; red[uq][3][dl] = a3;
  __syncthreads();
  if (uq == 0) {
    #pragma unroll
    for (int s = 0; s < 4; ++s) {
      float v = red[0][s][dl] + red[1][s][dl] + red[2][s][dl] + red[3][s][dl];
      xo[s*DD + d] = (lens[s] > 0) ? v : empty[d];
    }
  }
}

// ---------------------------------------------------------------------------
// Stage 4a: entity matvecs (HBM-bound, 302 MB fp32 weights).
// ---------------------------------------------------------------------------
__global__ __launch_bounds__(256) void ent_matvec(
    const float* __restrict__ x,
    const float* __restrict__ Wn, const float* __restrict__ Wg,
    float* __restrict__ yn, float* __restrict__ yg)
{
  __shared__ float xs[192];
  const int db = blockIdx.x;
  const int kb = blockIdx.y;
  const int tid = threadIdx.x;
  if (tid < 192) xs[tid] = x[kb*192 + tid];
  __syncthreads();
  const int d = db*256 + tid;
  float an = 0.f, ag = 0.f;
  size_t base = (size_t)kb * 192 * DE + d;
  for (int kk = 0; kk < 192; ++kk) {
    float xv = xs[kk];
    an = fmaf(xv, Wn[base + (size_t)kk*DE], an);
    ag = fmaf(xv, Wg[base + (size_t)kk*DE], ag);
  }
  atomicAdd(&yn[d], an);
  atomicAdd(&yg[d], ag);
}

// ---------------------------------------------------------------------------
// Stage 4b: entity highway + logits + softmax -> out[2].
// ---------------------------------------------------------------------------
__global__ __launch_bounds__(256) void final_kernel(
    const float* __restrict__ x, const float* __restrict__ yn,
    const float* __restrict__ yg, const float* __restrict__ bn,
    const float* __restrict__ bg, const float* __restrict__ Wl,
    const float* __restrict__ bl, float* __restrict__ out)
{
  const int tid = threadIdx.x;
  float a0 = 0.f, a1 = 0.f;
  for (int p = 0; p < DE/256; ++p) {
    int d = p*256 + tid;
    float n  = yn[d] + bn[d];
    float gp = yg[d] + bg[d];
    float h  = fmaxf(n, 0.f);
    float g  = 1.f / (1.f + __expf(-gp));
    float hw = h*g + (1.f - g)*x[d];
    a0 += hw * Wl[d*2 + 0];
    a1 += hw * Wl[d*2 + 1];
  }
  #pragma unroll
  for (int mm = 1; mm < 64; mm <<= 1) {
    a0 += __shfl_xor(a0, mm, 64);
    a1 += __shfl_xor(a1, mm, 64);
  }
  __shared__ float s0[4], s1[4];
  if ((tid & 63) == 0) { s0[tid>>6] = a0; s1[tid>>6] = a1; }
  __syncthreads();
  if (tid == 0) {
    for (int w = 1; w < 4; ++w) { a0 += s0[w]; a1 += s1[w]; }
    float l0 = a0 + bl[0], l1 = a1 + bl[1];
    float m = fmaxf(l0, l1);
    float e0 = __expf(l0 - m), e1 = __expf(l1 - m);
    out[0] = e0 / (e0 + e1);
    out[1] = e1 / (e0 + e1);
  }
}

// ---------------------------------------------------------------------------
extern "C" void kernel_launch(void* const* d_in, const int* in_sizes, int n_in,
                              void* d_out, int out_size, void* d_ws, size_t ws_size,
                              hipStream_t stream) {
  const float* Lemb   = (const float*)d_in[0];
  const float* Remb   = (const float*)d_in[1];
  const float* Wn_tok = (const float*)d_in[2];
  const float* bn_tok = (const float*)d_in[3];
  const float* Wg_tok = (const float*)d_in[4];
  const float* bg_tok = (const float*)d_in[5];
  const float* Wl_tok = (const float*)d_in[6];
  // d_in[7] = b_lin_tok: constant shift, argmax-invariant -> unused
  const float* AEl    = (const float*)d_in[8];
  const float* AEr    = (const float*)d_in[9];
  const float* Wn_ent = (const float*)d_in[10];
  const float* bn_ent = (const float*)d_in[11];
  const float* Wg_ent = (const float*)d_in[12];
  const float* bg_ent = (const float*)d_in[13];
  const float* Wl_ent = (const float*)d_in[14];
  const float* bl_ent = (const float*)d_in[15];
  const float* empty  = (const float*)d_in[16];
  const int*   lensL  = (const int*)d_in[17];
  const int*   lensR  = (const int*)d_in[18];

  char* ws = (char*)d_ws;
  float* S    = (float*)(ws + 0);        // 65536 f
  int*  idxL  = (int*)  (ws + 262144);   // 256
  int*  idxR  = (int*)  (ws + 263168);   // 256
  float* x    = (float*)(ws + 264192);   // 6144 f
  float* yn   = (float*)(ws + 288768);   // 6144 f
  float* yg   = (float*)(ws + 313344);   // 6144 f (contiguous with yn)
  float* wSm  = (float*)(ws + 337920);   // 512 f
  int*  segA  = (int*)  (ws + 339968);   // 512
  _Float16* WnT = (_Float16*)(ws + 342016);   // 768*768 f16
  _Float16* WgT = (_Float16*)(ws + 1521664);  // 768*768 f16

  hipMemsetAsync(S, 0, (size_t)NT*NT*sizeof(float), stream);
  hipMemsetAsync(yn, 0, (size_t)2*DE*sizeof(float), stream);

  transpose_cvt<<<dim3(24, 24, 2), 256, 0, stream>>>(Wn_tok, Wg_tok, WnT, WgT);
  score_mfma<<<dim3(2, 6, NT), 256, 0, stream>>>(
      Lemb, Remb, WnT, WgT, bn_tok, bg_tok, Wl_tok, S);
  argmax_kernel<<<512, 256, 0, stream>>>(S, idxL, idxR);
  attr_score<<<2, 256, 0, stream>>>(Lemb, Remb, AEl, AEr, lensL, lensR, wSm, segA);
  attr_reduce<<<dim3(2, 12), 256, 0, stream>>>(
      Lemb, Remb, lensL, lensR, idxL, idxR, wSm, segA, empty, x);
  ent_matvec<<<dim3(24, 32), 256, 0, stream>>>(x, Wn_ent, Wg_ent, yn, yg);
  final_kernel<<<1, 256, 0, stream>>>(
      x, yn, yg, bn_ent, bg_ent, Wl_ent, bl_ent, (float*)d_out);
}